// Round 3
// baseline (499.084 us; speedup 1.0000x reference)
//
#include <hip/hip_runtime.h>
#include <hip/hip_bf16.h>

typedef __bf16 bf16;
typedef __bf16 bf16x8 __attribute__((ext_vector_type(8)));
typedef __bf16 bf16x4 __attribute__((ext_vector_type(4)));
typedef float f32x4 __attribute__((ext_vector_type(4)));

#define MFMA16(a, b, c) __builtin_amdgcn_mfma_f32_16x16x32_bf16((a), (b), (c), 0, 0, 0)

// ws layout (bytes)
static constexpr size_t FEAT_OFF = 0;                    // 4,194,304 bf16 = 8,388,608 B
static constexpr size_t OMW3_OFF = 8388608;              // 995,328 bf16  = 1,990,656 B
static constexpr size_t OMB_OFF  = OMW3_OFF + 1990656;   // 1728 f32      = 6,912 B
static constexpr size_t DCW2_OFF = OMB_OFF + 6912;       // 36,864 bf16   = 73,728 B

// ---------------- prep kernels ----------------
__global__ void prep_cvt(const float* __restrict__ in, bf16* __restrict__ out, int n) {
    int i = blockIdx.x * 256 + threadIdx.x;
    if (i < n) out[i] = (bf16)in[i];
}

// om_w -> MFMA-fragment order: omw3[ctile 36][kk 18][t 3][lane 64][j 8]
__global__ void prep_omw3(const float* __restrict__ om_w, bf16* __restrict__ out) {
    int i = blockIdx.x * 256 + threadIdx.x;
    if (i >= 995328) return;
    int e = i & 511, lane = e >> 3, j = e & 7;
    int q = i >> 9;              // (ct*18+kk)*3 + t
    int t = q % 3, q2 = q / 3, kk = q2 % 18, ct = q2 / 18;
    int ck = ct * 16 + (lane & 15);
    int kcol = kk * 32 + (lane >> 4) * 8 + j;
    int tap = kcol >> 6, cf = kcol & 63;
    int ch = (t < 2) ? (ck * 2 + t) : (1152 + ck);
    out[i] = (bf16)om_w[ch * 576 + cf * 9 + tap];
}

// dc_w -> permuted-K fragment order: dcw2[win 18][ot 4][lane 64][j 8]
__global__ void prep_dcw2(const float* __restrict__ dc_w, const float* __restrict__ om_b,
                          bf16* __restrict__ dcw2, float* __restrict__ ombr) {
    int i = blockIdx.x * 256 + threadIdx.x;
    if (i < 36864) {
        int e = i & 511, lane = e >> 3, j = e & 7;
        int q = i >> 9;          // win*4 + ot
        int ot = q & 3, win = q >> 2;
        int o = ot * 16 + (lane & 15), gg = lane >> 4;
        int ck = win * 32 + ((j < 4) ? (gg * 4 + j) : (16 + gg * 4 + (j - 4)));
        dcw2[i] = (bf16)dc_w[o * 576 + ck];
    }
    if (i < 1728) {
        int t = i / 576, ck = i - t * 576;
        int ch = (t < 2) ? (ck * 2 + t) : (1152 + ck);
        ombr[i] = om_b[ch];
    }
}

// ---------------- fused main kernel ----------------
// One wg per (b,h), 4 waves = (px-half, ck-half). Barrier-free main loop:
// GEMM1 (frag-packed A, swizzled-LDS feat B) -> bilinear sample + mask ->
// GEMM2 straight from registers (permuted-K A), acc2 partial over K-slices.
// Epilogue: ck-half pair reduce via LDS, bias+relu, store.

__global__ void __launch_bounds__(256, 2)
deform_fused(const float* __restrict__ inputs,
             const bf16* __restrict__ featbf,
             const bf16* __restrict__ omw3,
             const float* __restrict__ ombr,
             const bf16* __restrict__ dcw2,
             const float* __restrict__ dcb,
             float* __restrict__ out)
{
    const int bh = blockIdx.x;
    const int b = bh >> 7, h = bh & 127;
    const int tid = threadIdx.x;
    const int lane = tid & 63, wid = tid >> 6;
    const int l15 = lane & 15, g = lane >> 4;
    const int ckh = wid & 1, pxh = wid >> 1;

    __shared__ __align__(16) unsigned char smem[49920];

    for (int i = tid; i < 12480; i += 256) ((unsigned*)smem)[i] = 0u;
    __syncthreads();
    if (tid < 192) {
        const int ky = tid >> 6, cf = tid & 63;
        const int hh = h - 1 + ky;
        if ((unsigned)hh < 128u) {
            const bf16* src = featbf + (size_t)((b * 64 + cf) * 128 + hh) * 128;
            const int cfb = cf >> 3, cfl = (cf & 7) << 1;
            for (int c0 = 0; c0 < 128; c0 += 8) {
                bf16x8 v = *(const bf16x8*)(src + c0);
#pragma unroll
                for (int e = 0; e < 8; ++e) {
                    int pc = c0 + e + 1;
                    *(bf16*)(smem + (ky * 130 + pc) * 128 + ((cfb ^ (pc & 7)) << 4) + cfl) = v[e];
                }
            }
        }
    }
    __syncthreads();

    f32x4 acc2[4][4];
#pragma unroll
    for (int ot = 0; ot < 4; ++ot)
#pragma unroll
        for (int nf = 0; nf < 4; ++nf) acc2[ot][nf] = (f32x4){0.f, 0.f, 0.f, 0.f};

    for (int blk = 0; blk < 9; ++blk) {
        f32x4 acc1[3][2][4];
#pragma unroll
        for (int t = 0; t < 3; ++t)
#pragma unroll
            for (int ct = 0; ct < 2; ++ct)
#pragma unroll
                for (int nf = 0; nf < 4; ++nf) acc1[t][ct][nf] = (f32x4){0.f, 0.f, 0.f, 0.f};

        const int ct0 = blk * 4 + ckh * 2;

#pragma unroll 2
        for (int kk = 0; kk < 18; ++kk) {
            const int tap = kk >> 1;
            const int kyp = tap / 3, kxp = tap - 3 * kyp;
            bf16x8 a[2][3];
#pragma unroll
            for (int ct = 0; ct < 2; ++ct)
#pragma unroll
                for (int t = 0; t < 3; ++t)
                    a[ct][t] = *(const bf16x8*)(omw3
                        + (size_t)((((ct0 + ct) * 18 + kk) * 3 + t) * 512) + lane * 8);
            const int pcb = pxh * 64 + l15 + kxp;
            const int base = (kyp * 130 + pcb) * 128 + ((((kk & 1) * 4 + g) ^ (pcb & 7)) << 4);
#pragma unroll
            for (int nf = 0; nf < 4; ++nf) {
                bf16x8 bfr = *(const bf16x8*)(smem + base + nf * 2048);
#pragma unroll
                for (int ct = 0; ct < 2; ++ct) {
                    acc1[0][ct][nf] = MFMA16(a[ct][0], bfr, acc1[0][ct][nf]);
                    acc1[1][ct][nf] = MFMA16(a[ct][1], bfr, acc1[1][ct][nf]);
                    acc1[2][ct][nf] = MFMA16(a[ct][2], bfr, acc1[2][ct][nf]);
                }
            }
        }

        bf16x8 aK[4];
#pragma unroll
        for (int ot = 0; ot < 4; ++ot)
            aK[ot] = *(const bf16x8*)(dcw2 + (size_t)(((blk * 2 + ckh) * 4 + ot) * 512) + lane * 8);

        bf16x4 p[2][4];
#pragma unroll
        for (int ct = 0; ct < 2; ++ct) {
            int cpl[4], dyv[4], dxv[4];
            float by[4], bx[4], bm[4];
#pragma unroll
            for (int r = 0; r < 4; ++r) {
                int ck = blk * 64 + ckh * 32 + ct * 16 + g * 4 + r;
                int c = ck / 9, kd = ck - 9 * c, kq = kd / 3;
                cpl[r] = c; dyv[r] = kq - 1; dxv[r] = kd - 3 * kq - 1;
                by[r] = ombr[ck]; bx[r] = ombr[576 + ck]; bm[r] = ombr[1152 + ck];
            }
#pragma unroll
            for (int nf = 0; nf < 4; ++nf) {
                float s[4];
#pragma unroll
                for (int r = 0; r < 4; ++r) {
                    float offy = acc1[0][ct][nf][r] + by[r];
                    float offx = acc1[1][ct][nf][r] + bx[r];
                    float lg   = acc1[2][ct][nf][r] + bm[r];
                    float py = (float)(h + dyv[r]) + offy;
                    float px = (float)(pxh * 64 + nf * 16 + l15 + dxv[r]) + offx;
                    float y0f = floorf(py), x0f = floorf(px);
                    float wy = py - y0f, wx = px - x0f;
                    int y0 = (int)y0f, x0 = (int)x0f;
                    int y1 = y0 + 1, x1 = x0 + 1;
                    const float* pl = inputs + ((size_t)(b * 64 + cpl[r]) << 14);
                    int y0c = min(max(y0, 0), 127), y1c = min(max(y1, 0), 127);
                    int x0c = min(max(x0, 0), 127), x1c = min(max(x1, 0), 127);
                    bool vy0 = (unsigned)y0 < 128u, vy1 = (unsigned)y1 < 128u;
                    bool vx0 = (unsigned)x0 < 128u, vx1 = (unsigned)x1 < 128u;
                    float v00 = (vy0 && vx0) ? pl[(y0c << 7) + x0c] : 0.f;
                    float v01 = (vy0 && vx1) ? pl[(y0c << 7) + x1c] : 0.f;
                    float v10 = (vy1 && vx0) ? pl[(y1c << 7) + x0c] : 0.f;
                    float v11 = (vy1 && vx1) ? pl[(y1c << 7) + x1c] : 0.f;
                    float bil = (1.f - wy) * ((1.f - wx) * v00 + wx * v01)
                              + wy * ((1.f - wx) * v10 + wx * v11);
                    float msk = __builtin_amdgcn_rcpf(1.f + __expf(-lg));
                    s[r] = bil * msk;
                }
                p[ct][nf] = (bf16x4){(bf16)s[0], (bf16)s[1], (bf16)s[2], (bf16)s[3]};
            }
        }

#pragma unroll
        for (int nf = 0; nf < 4; ++nf) {
            bf16x8 bfr = __builtin_shufflevector(p[0][nf], p[1][nf], 0, 1, 2, 3, 4, 5, 6, 7);
#pragma unroll
            for (int ot = 0; ot < 4; ++ot)
                acc2[ot][nf] = MFMA16(aK[ot], bfr, acc2[ot][nf]);
        }
    }

    // ---- epilogue ----
    __syncthreads();
    float* red = (float*)smem;  // [2 pxh][64 o][68] = 34,816 B
    if (ckh == 0) {
#pragma unroll
        for (int ot = 0; ot < 4; ++ot)
#pragma unroll
            for (int nf = 0; nf < 4; ++nf)
#pragma unroll
                for (int r = 0; r < 4; ++r)
                    red[pxh * 4352 + (ot * 16 + g * 4 + r) * 68 + nf * 16 + l15] = acc2[ot][nf][r];
    }
    __syncthreads();
    if (ckh == 1) {
#pragma unroll
        for (int ot = 0; ot < 4; ++ot)
#pragma unroll
            for (int nf = 0; nf < 4; ++nf)
#pragma unroll
                for (int r = 0; r < 4; ++r)
                    red[pxh * 4352 + (ot * 16 + g * 4 + r) * 68 + nf * 16 + l15] += acc2[ot][nf][r];
    }
    __syncthreads();
    for (int i = tid; i < 8192; i += 256) {
        int pair = i >> 12, rem = i & 4095, o = rem >> 6, pxl = rem & 63;
        float v = red[pair * 4352 + o * 68 + pxl] + dcb[o];
        out[((size_t)(b * 64 + o) * 128 + h) * 128 + pair * 64 + pxl] = fmaxf(v, 0.f);
    }
}

// ---------------- launcher ----------------
extern "C" void kernel_launch(void* const* d_in, const int* in_sizes, int n_in,
                              void* d_out, int out_size, void* d_ws, size_t ws_size,
                              hipStream_t stream) {
    const float* inputs = (const float*)d_in[0];
    const float* feat   = (const float*)d_in[1];
    const float* om_w   = (const float*)d_in[2];
    const float* om_b   = (const float*)d_in[3];
    const float* dc_w   = (const float*)d_in[4];
    const float* dc_b   = (const float*)d_in[5];
    float* out = (float*)d_out;

    char* ws = (char*)d_ws;
    bf16*  featbf = (bf16*)(ws + FEAT_OFF);
    bf16*  omw3   = (bf16*)(ws + OMW3_OFF);
    float* ombr   = (float*)(ws + OMB_OFF);
    bf16*  dcw2   = (bf16*)(ws + DCW2_OFF);

    prep_cvt<<<(4194304 + 255) / 256, 256, 0, stream>>>(feat, featbf, 4194304);
    prep_omw3<<<(995328 + 255) / 256, 256, 0, stream>>>(om_w, omw3);
    prep_dcw2<<<(36864 + 255) / 256, 256, 0, stream>>>(dc_w, om_b, dcw2, ombr);

    deform_fused<<<512, 256, 0, stream>>>(inputs, featbf, omw3, ombr, dcw2, dc_b, out);
}

// Round 4
// 181.248 us; speedup vs baseline: 2.7536x; 2.7536x over previous
//
#include <hip/hip_runtime.h>
#include <hip/hip_bf16.h>

typedef __bf16 bf16;
typedef __bf16 bf16x8 __attribute__((ext_vector_type(8)));
typedef __bf16 bf16x4 __attribute__((ext_vector_type(4)));
typedef float f32x4 __attribute__((ext_vector_type(4)));

#define MFMA16(a, b, c) __builtin_amdgcn_mfma_f32_16x16x32_bf16((a), (b), (c), 0, 0, 0)

// ---- ws layout (bytes) ----
static constexpr size_t FEAT_OFF = 0;                    // 4,194,304 bf16 = 8,388,608
static constexpr size_t OMW3_OFF = 8388608;              // 995,328 bf16   = 1,990,656
static constexpr size_t OMB_OFF  = OMW3_OFF + 1990656;   // 1728 f32       = 6,912
static constexpr size_t DCW_OFF  = OMB_OFF + 6912;       // 36,864 bf16    = 73,728
static constexpr size_t PAD_OFF  = DCW_OFF + 73728;      // 256*134*134 f32 = 18,386,944
// total ~28.8 MB

// ---------------- prep kernels ----------------
__global__ void prep_cvt(const float* __restrict__ in, bf16* __restrict__ out, int n) {
    int i = blockIdx.x * 256 + threadIdx.x;
    if (i < n) out[i] = (bf16)in[i];
}

// om_w -> MFMA-fragment order: omw3[ctile 36][kk 18][t 3][lane 64][j 8]
__global__ void prep_omw3(const float* __restrict__ om_w, bf16* __restrict__ out) {
    int i = blockIdx.x * 256 + threadIdx.x;
    if (i >= 995328) return;
    int e = i & 511, lane = e >> 3, j = e & 7;
    int q = i >> 9;              // (ct*18+kk)*3 + t
    int t = q % 3, q2 = q / 3, kk = q2 % 18, ct = q2 / 18;
    int ck = ct * 16 + (lane & 15);
    int kcol = kk * 32 + (lane >> 4) * 8 + j;
    int tap = kcol >> 6, cf = kcol & 63;
    int ch = (t < 2) ? (ck * 2 + t) : (1152 + ck);
    out[i] = (bf16)om_w[ch * 576 + cf * 9 + tap];
}

// dc_w -> plain-K fragment order: dcw2p[win 18][ot 4][lane 64][j 8]
// o = ot*16 + (lane&15); ck = win*32 + (lane>>4)*8 + j
__global__ void prep_dcw2p(const float* __restrict__ dc_w, const float* __restrict__ om_b,
                           bf16* __restrict__ dcw2p, float* __restrict__ ombr) {
    int i = blockIdx.x * 256 + threadIdx.x;
    if (i < 36864) {
        int j = i & 7, lane = (i >> 3) & 63, ot = (i >> 9) & 3, win = i >> 11;
        int o = ot * 16 + (lane & 15);
        int ck = win * 32 + (lane >> 4) * 8 + j;
        dcw2p[i] = (bf16)dc_w[o * 576 + ck];
    }
    if (i < 1728) {
        int t = i / 576, ck = i - t * 576;
        int ch = (t < 2) ? (ck * 2 + t) : (1152 + ck);
        ombr[i] = om_b[ch];
    }
}

// inputs [256][128][128] -> zero-padded pad [256][134][134] (3-px border)
__global__ void prep_pad(const float* __restrict__ inputs, float* __restrict__ pad) {
    int yy = blockIdx.x, bc = blockIdx.y, xx = threadIdx.x;
    if (xx >= 134) return;
    float v = 0.f;
    if (yy >= 3 && yy <= 130 && xx >= 3 && xx <= 130)
        v = inputs[(size_t)bc * 16384 + (yy - 3) * 128 + (xx - 3)];
    pad[((size_t)bc * 134 + yy) * 134 + xx] = v;
}

// ---------------- fused main kernel ----------------
// wg per (b,h); 4 waves = (ckh, pxh): each wave 32 cks x 64 px for GEMM1/sample,
// 16 o x 128 px for GEMM2 (acc2[8]=32 regs, full K per blk via sampB exchange).
// 2 barriers per blk. Bilinear from pre-padded image (no bounds logic).

__global__ void __launch_bounds__(256) __attribute__((amdgpu_waves_per_eu(2, 2)))
deform_fused(const float* __restrict__ pad,
             const bf16* __restrict__ featbf,
             const bf16* __restrict__ omw3,
             const float* __restrict__ ombr,
             const bf16* __restrict__ dcw2p,
             const float* __restrict__ dcb,
             float* __restrict__ out)
{
    const int bh = blockIdx.x;
    const int b = bh >> 7, h = bh & 127;
    const int tid = threadIdx.x;
    const int lane = tid & 63, wid = tid >> 6;
    const int l15 = lane & 15, g = lane >> 4;
    const int ckh = wid & 1, pxh = wid >> 1;

    __shared__ __align__(16) unsigned char smem[49920 + 16384];
    char* featB = (char*)smem;
    char* sampB = (char*)smem + 49920;

    // zero feat patch (pads must stay 0)
    for (int i = tid; i < 12480; i += 256) ((unsigned*)featB)[i] = 0u;
    __syncthreads();
    // stage feat rows h-1..h+1 : byte = (ky*130+pc)*128 + ((cfb ^ (pc&7))<<4) + (cf&7)*2
    if (tid < 192) {
        const int ky = tid >> 6, cf = tid & 63;
        const int hh = h - 1 + ky;
        if ((unsigned)hh < 128u) {
            const bf16* src = featbf + (size_t)((b * 64 + cf) * 128 + hh) * 128;
            const int cfb = cf >> 3, cfl = (cf & 7) << 1;
            for (int c0 = 0; c0 < 128; c0 += 8) {
                bf16x8 v = *(const bf16x8*)(src + c0);
#pragma unroll
                for (int e = 0; e < 8; ++e) {
                    int pc = c0 + e + 1;
                    *(bf16*)(featB + (ky * 130 + pc) * 128 + ((cfb ^ (pc & 7)) << 4) + cfl) = v[e];
                }
            }
        }
    }
    __syncthreads();

    f32x4 acc2[8];
#pragma unroll
    for (int u = 0; u < 8; ++u) acc2[u] = (f32x4){0.f, 0.f, 0.f, 0.f};

    const float* padb = pad + (size_t)b * 64 * 17956 + 405;  // +405 = (3*134+3) border fold
    const float fx0 = (float)(pxh * 64 + l15);

#pragma unroll 1
    for (int blk = 0; blk < 9; ++blk) {
        // ---- GEMM1: 32 cks (2 ck-tiles) x 3 types x 64 px ----
        f32x4 acc1[3][2][4];
#pragma unroll
        for (int t = 0; t < 3; ++t)
#pragma unroll
            for (int ct = 0; ct < 2; ++ct)
#pragma unroll
                for (int nf = 0; nf < 4; ++nf) acc1[t][ct][nf] = (f32x4){0.f, 0.f, 0.f, 0.f};

        const int ct0 = blk * 4 + ckh * 2;

#pragma unroll 2
        for (int kk = 0; kk < 18; ++kk) {
            const int tap = kk >> 1;
            const int kyp = tap / 3, kxp = tap - 3 * kyp;
            const int pcb = pxh * 64 + l15 + kxp;
            const int base = (kyp * 130 + pcb) * 128 + ((((kk & 1) * 4 + g) ^ (pcb & 7)) << 4);
            bf16x8 a0[3], a1[3];
#pragma unroll
            for (int t = 0; t < 3; ++t) {
                a0[t] = *(const bf16x8*)(omw3 + (size_t)(((ct0 * 18 + kk) * 3 + t) * 512) + lane * 8);
                a1[t] = *(const bf16x8*)(omw3 + (size_t)((((ct0 + 1) * 18 + kk) * 3 + t) * 512) + lane * 8);
            }
#pragma unroll
            for (int nf = 0; nf < 4; ++nf) {
                bf16x8 bfr = *(const bf16x8*)(featB + base + nf * 2048);
                acc1[0][0][nf] = MFMA16(a0[0], bfr, acc1[0][0][nf]);
                acc1[1][0][nf] = MFMA16(a0[1], bfr, acc1[1][0][nf]);
                acc1[2][0][nf] = MFMA16(a0[2], bfr, acc1[2][0][nf]);
                acc1[0][1][nf] = MFMA16(a1[0], bfr, acc1[0][1][nf]);
                acc1[1][1][nf] = MFMA16(a1[1], bfr, acc1[1][1][nf]);
                acc1[2][1][nf] = MFMA16(a1[2], bfr, acc1[2][1][nf]);
            }
        }

        // GEMM2 A-frags (independent; issue early)
        bf16x8 aK0 = *(const bf16x8*)(dcw2p + (size_t)(((blk * 2 + 0) * 4 + wid) * 512) + lane * 8);
        bf16x8 aK1 = *(const bf16x8*)(dcw2p + (size_t)(((blk * 2 + 1) * 4 + wid) * 512) + lane * 8);

        // ---- sample (bilinear from padded image + sigmoid mask) ----
#pragma unroll
        for (int ct = 0; ct < 2; ++ct) {
            const float* pl[4];
            float bye[4], bxe[4], bm[4];
#pragma unroll
            for (int r = 0; r < 4; ++r) {
                int ck = blk * 64 + ckh * 32 + ct * 16 + g * 4 + r;
                int c = ck / 9, kd = ck - 9 * c, kq = kd / 3;
                pl[r] = padb + (size_t)c * 17956;
                bye[r] = ombr[ck] + (float)(h + kq - 1);
                bxe[r] = ombr[576 + ck] + (float)(kd - 3 * kq - 1);
                bm[r]  = ombr[1152 + ck];
            }
#pragma unroll
            for (int nf = 0; nf < 4; ++nf) {
                const float fxn = fx0 + 16.f * (float)nf;
                float s[4];
#pragma unroll
                for (int r = 0; r < 4; ++r) {
                    float py = acc1[0][ct][nf][r] + bye[r];
                    float px = acc1[1][ct][nf][r] + bxe[r] + fxn;
                    float lg = acc1[2][ct][nf][r] + bm[r];
                    py = fminf(fmaxf(py, -2.5f), 129.5f);
                    px = fminf(fmaxf(px, -2.5f), 129.5f);
                    float y0f = floorf(py), x0f = floorf(px);
                    float wy = py - y0f, wx = px - x0f;
                    int idx = (int)y0f * 134 + (int)x0f;
                    const float* p0 = pl[r] + idx;
                    float v00 = p0[0], v01 = p0[1], v10 = p0[134], v11 = p0[135];
                    float top = v00 + wx * (v01 - v00);
                    float bot = v10 + wx * (v11 - v10);
                    float bil = top + wy * (bot - top);
                    float msk = __builtin_amdgcn_rcpf(1.f + __expf(-lg));
                    s[r] = bil * msk;
                }
                bf16x4 p = {(bf16)s[0], (bf16)s[1], (bf16)s[2], (bf16)s[3]};
                // px-row = pxh*64+nf*16+l15 ; logical 8B block = ckh*8+ct*4+g, XOR-swizzled
                *(bf16x4*)(sampB + (pxh * 64 + nf * 16 + l15) * 128
                           + (((ckh * 8 + ct * 4 + g) ^ ((l15 & 7) << 1)) << 3)) = p;
            }
        }
        __syncthreads();

        // ---- GEMM2: o = wid*16.., full 128 px, K=64 (this blk) ----
#pragma unroll
        for (int u = 0; u < 8; ++u) {
            const int rb = (u * 16 + l15) * 128;
            bf16x8 b0 = *(const bf16x8*)(sampB + rb + ((g ^ (l15 & 7)) << 4));
            bf16x8 b1 = *(const bf16x8*)(sampB + rb + (((4 + g) ^ (l15 & 7)) << 4));
            acc2[u] = MFMA16(aK0, b0, acc2[u]);
            acc2[u] = MFMA16(aK1, b1, acc2[u]);
        }
        __syncthreads();
    }

    // ---- epilogue: bias + relu, direct coalesced stores ----
    float bias[4];
#pragma unroll
    for (int r = 0; r < 4; ++r) bias[r] = dcb[wid * 16 + g * 4 + r];
#pragma unroll
    for (int u = 0; u < 8; ++u)
#pragma unroll
        for (int r = 0; r < 4; ++r) {
            int o = wid * 16 + g * 4 + r;
            out[((size_t)(b * 64 + o) * 128 + h) * 128 + u * 16 + l15]
                = fmaxf(acc2[u][r] + bias[r], 0.f);
        }
}

// ---------------- launcher ----------------
extern "C" void kernel_launch(void* const* d_in, const int* in_sizes, int n_in,
                              void* d_out, int out_size, void* d_ws, size_t ws_size,
                              hipStream_t stream) {
    const float* inputs = (const float*)d_in[0];
    const float* feat   = (const float*)d_in[1];
    const float* om_w   = (const float*)d_in[2];
    const float* om_b   = (const float*)d_in[3];
    const float* dc_w   = (const float*)d_in[4];
    const float* dc_b   = (const float*)d_in[5];
    float* out = (float*)d_out;

    char* ws = (char*)d_ws;
    bf16*  featbf = (bf16*)(ws + FEAT_OFF);
    bf16*  omw3   = (bf16*)(ws + OMW3_OFF);
    float* ombr   = (float*)(ws + OMB_OFF);
    bf16*  dcw2p  = (bf16*)(ws + DCW_OFF);
    float* pad    = (float*)(ws + PAD_OFF);

    prep_cvt<<<(4194304 + 255) / 256, 256, 0, stream>>>(feat, featbf, 4194304);
    prep_omw3<<<(995328 + 255) / 256, 256, 0, stream>>>(om_w, omw3);
    prep_dcw2p<<<(36864 + 255) / 256, 256, 0, stream>>>(dc_w, om_b, dcw2p, ombr);
    prep_pad<<<dim3(134, 256), 256, 0, stream>>>(inputs, pad);

    deform_fused<<<512, 256, 0, stream>>>(pad, featbf, omw3, ombr, dcw2p, dc_b, out);
}

// Round 5
// 180.873 us; speedup vs baseline: 2.7593x; 1.0021x over previous
//
#include <hip/hip_runtime.h>
#include <hip/hip_bf16.h>

typedef __bf16 bf16;
typedef __bf16 bf16x8 __attribute__((ext_vector_type(8)));
typedef __bf16 bf16x4 __attribute__((ext_vector_type(4)));
typedef float f32x4 __attribute__((ext_vector_type(4)));
typedef int i32x4 __attribute__((ext_vector_type(4)));

#define MFMA16(a, b, c) __builtin_amdgcn_mfma_f32_16x16x32_bf16((a), (b), (c), 0, 0, 0)

// ---- ws layout (bytes) ----
static constexpr size_t FEATS_OFF = 0;                    // featS: 4,194,304 bf16 = 8,388,608
static constexpr size_t OMW3_OFF  = 8388608;              // 995,328 bf16   = 1,990,656
static constexpr size_t OMB_OFF   = OMW3_OFF + 1990656;   // 1728 f32       = 6,912
static constexpr size_t DCW_OFF   = OMB_OFF + 6912;       // 36,864 bf16    = 73,728
static constexpr size_t PAD_OFF   = DCW_OFF + 73728;      // 256*134*134 f32 = 18,386,944

// ---------------- prep kernels ----------------

// feat [b][cf][hh][px] f32 -> featS [b][hh][px][cf swizzled] bf16
// swizzle within 128B row: elements cf=cfb*8+e at 16B-block (cfb ^ (px&7)), pos e
__global__ void prep_featS(const float* __restrict__ feat, bf16* __restrict__ featS) {
    const int hh = blockIdx.x, b = blockIdx.y;
    __shared__ float t[64][129];
    for (int i = threadIdx.x; i < 64 * 32; i += 256) {
        int cf = i >> 5, q = i & 31;
        const float* src = feat + ((size_t)(b * 64 + cf) * 128 + hh) * 128 + q * 4;
        t[cf][q * 4 + 0] = src[0];
        t[cf][q * 4 + 1] = src[1];
        t[cf][q * 4 + 2] = src[2];
        t[cf][q * 4 + 3] = src[3];
    }
    __syncthreads();
    for (int i = threadIdx.x; i < 1024; i += 256) {
        int px = i >> 3, cfb = i & 7;
        int sb = cfb ^ (px & 7);
        bf16x8 v;
#pragma unroll
        for (int e = 0; e < 8; ++e) v[e] = (bf16)t[cfb * 8 + e][px];
        *(bf16x8*)(featS + ((size_t)((b * 128 + hh) * 128 + px) << 6) + sb * 8) = v;
    }
}

// om_w -> MFMA-fragment order: omw3[ctile 36][kk 18][t 3][lane 64][j 8]
__global__ void prep_omw3(const float* __restrict__ om_w, bf16* __restrict__ out) {
    int i = blockIdx.x * 256 + threadIdx.x;
    if (i >= 995328) return;
    int e = i & 511, lane = e >> 3, j = e & 7;
    int q = i >> 9;              // (ct*18+kk)*3 + t
    int t = q % 3, q2 = q / 3, kk = q2 % 18, ct = q2 / 18;
    int ck = ct * 16 + (lane & 15);
    int kcol = kk * 32 + (lane >> 4) * 8 + j;
    int tap = kcol >> 6, cf = kcol & 63;
    int ch = (t < 2) ? (ck * 2 + t) : (1152 + ck);
    out[i] = (bf16)om_w[ch * 576 + cf * 9 + tap];
}

// dc_w -> plain-K fragment order: dcw2p[win 18][ot 4][lane 64][j 8]
__global__ void prep_dcw2p(const float* __restrict__ dc_w, const float* __restrict__ om_b,
                           bf16* __restrict__ dcw2p, float* __restrict__ ombr) {
    int i = blockIdx.x * 256 + threadIdx.x;
    if (i < 36864) {
        int j = i & 7, lane = (i >> 3) & 63, ot = (i >> 9) & 3, win = i >> 11;
        int o = ot * 16 + (lane & 15);
        int ck = win * 32 + (lane >> 4) * 8 + j;
        dcw2p[i] = (bf16)dc_w[o * 576 + ck];
    }
    if (i < 1728) {
        int t = i / 576, ck = i - t * 576;
        int ch = (t < 2) ? (ck * 2 + t) : (1152 + ck);
        ombr[i] = om_b[ch];
    }
}

// inputs [256][128][128] -> zero-padded pad [256][134][134] (3-px border)
__global__ void prep_pad(const float* __restrict__ inputs, float* __restrict__ pad) {
    int yy = blockIdx.x, bc = blockIdx.y, xx = threadIdx.x;
    if (xx >= 134) return;
    float v = 0.f;
    if (yy >= 3 && yy <= 130 && xx >= 3 && xx <= 130)
        v = inputs[(size_t)bc * 16384 + (yy - 3) * 128 + (xx - 3)];
    pad[((size_t)bc * 134 + yy) * 134 + xx] = v;
}

// ---------------- fused main kernel ----------------
// grid 1024 = (b, h, pxhalf); 4 waves = ck-quarters (wid). Per wave per blk:
// GEMM1 16 cks x 3 types x 64 px (acc1=48 regs) -> sample 16/lane -> sampB
// exchange -> GEMM2 16 o x 64 px (acc2=16 regs). LDS 33.5KB -> 4 wg/CU.

__global__ void __launch_bounds__(256, 4)
deform_fused(const float* __restrict__ pad,
             const bf16* __restrict__ featS,
             const bf16* __restrict__ omw3,
             const float* __restrict__ ombr,
             const bf16* __restrict__ dcw2p,
             const float* __restrict__ dcb,
             float* __restrict__ out)
{
    const int bid = blockIdx.x;
    const int P0 = (bid & 1) << 6;
    const int h = (bid >> 1) & 127;
    const int b = bid >> 8;
    const int tid = threadIdx.x;
    const int lane = tid & 63, wid = tid >> 6;
    const int l15 = lane & 15, g = lane >> 4;

    __shared__ __align__(16) unsigned char smem[25344 + 8192];
    char* featB = (char*)smem;           // [3 ky][66 q][128B], swizzle rides from featS
    char* sampB = (char*)smem + 25344;   // [64 px][128B = 64 ck]

    // zero featB (halo cols / OOB rows stay 0)
    for (int i = tid; i < 6336; i += 256) ((unsigned*)featB)[i] = 0u;
    __syncthreads();
    // bulk-stage 3 rows x 65 px-cols x 128B from featS
    {
        const int s0 = (P0 == 0) ? 0 : 63;
        const int q0 = (P0 == 0) ? 1 : 0;
        for (int i = tid; i < 1560; i += 256) {
            int ky = i / 520, rem = i - ky * 520, row = rem >> 3, c = rem & 7;
            int hh = h - 1 + ky;
            if ((unsigned)hh < 128u) {
                const char* src = (const char*)featS
                    + (((size_t)(b * 128 + hh) * 128 + s0 + row) << 7) + c * 16;
                *(i32x4*)(featB + ((ky * 66 + q0 + row) << 7) + c * 16) = *(const i32x4*)src;
            }
        }
    }
    __syncthreads();

    f32x4 acc2[4];
#pragma unroll
    for (int u = 0; u < 4; ++u) acc2[u] = (f32x4){0.f, 0.f, 0.f, 0.f};

    const float* padb0 = pad + (size_t)b * 64 * 17956;  // uniform base; 32-bit voffsets
    const float fx0 = (float)(P0 + l15);

#pragma unroll 1
    for (int blk = 0; blk < 9; ++blk) {
        // ---- GEMM1: this wave's 16 cks x 3 types x 64 px ----
        f32x4 acc1[3][4];
#pragma unroll
        for (int t = 0; t < 3; ++t)
#pragma unroll
            for (int nf = 0; nf < 4; ++nf) acc1[t][nf] = (f32x4){0.f, 0.f, 0.f, 0.f};

        const int ct = blk * 4 + wid;

#pragma unroll 2
        for (int kk = 0; kk < 18; ++kk) {
            const int tap = kk >> 1;
            const int kyp = tap / 3, kxp = tap - 3 * kyp;
            bf16x8 a0 = *(const bf16x8*)(omw3 + (size_t)(((ct * 18 + kk) * 3 + 0) * 512) + lane * 8);
            bf16x8 a1 = *(const bf16x8*)(omw3 + (size_t)(((ct * 18 + kk) * 3 + 1) * 512) + lane * 8);
            bf16x8 a2 = *(const bf16x8*)(omw3 + (size_t)(((ct * 18 + kk) * 3 + 2) * 512) + lane * 8);
            const int q = l15 + kxp;  // + nf*16 added via nf*2048
            const int base = (kyp * 66 + q) * 128 + ((((kk & 1) * 4 + g) ^ ((q + 7) & 7)) << 4);
            bf16x8 bfr[4];
#pragma unroll
            for (int nf = 0; nf < 4; ++nf)
                bfr[nf] = *(const bf16x8*)(featB + base + nf * 2048);
            __builtin_amdgcn_s_setprio(1);
#pragma unroll
            for (int nf = 0; nf < 4; ++nf) {
                acc1[0][nf] = MFMA16(a0, bfr[nf], acc1[0][nf]);
                acc1[1][nf] = MFMA16(a1, bfr[nf], acc1[1][nf]);
                acc1[2][nf] = MFMA16(a2, bfr[nf], acc1[2][nf]);
            }
            __builtin_amdgcn_s_setprio(0);
        }

        // GEMM2 A-frags (independent, issue early)
        bf16x8 aK0 = *(const bf16x8*)(dcw2p + (size_t)(((blk * 2 + 0) * 4 + wid) * 512) + lane * 8);
        bf16x8 aK1 = *(const bf16x8*)(dcw2p + (size_t)(((blk * 2 + 1) * 4 + wid) * 512) + lane * 8);

        // ---- sample: 4 nf x 4 r per lane ----
        {
            unsigned coff[4];
            float bye3[4], bxe3[4], bm[4];
#pragma unroll
            for (int r = 0; r < 4; ++r) {
                int ck = blk * 64 + wid * 16 + g * 4 + r;
                int c = ck / 9, kd = ck - 9 * c, kq = kd / 3;
                coff[r] = (unsigned)(c * 17956);
                bye3[r] = ombr[ck] + (float)(h + kq + 2);            // ky-1+3 folded
                bxe3[r] = ombr[576 + ck] + (float)(kd - 3 * kq + 2); // kx-1+3 folded
                bm[r]   = ombr[1152 + ck];
            }
#pragma unroll
            for (int nf = 0; nf < 4; ++nf) {
                const float fxn = fx0 + 16.f * (float)nf;
                float s[4];
#pragma unroll
                for (int r = 0; r < 4; ++r) {
                    float py3 = acc1[0][nf][r] + bye3[r];
                    float px3 = acc1[1][nf][r] + bxe3[r] + fxn;
                    float lg  = acc1[2][nf][r] + bm[r];
                    py3 = fminf(fmaxf(py3, 0.5f), 132.5f);
                    px3 = fminf(fmaxf(px3, 0.5f), 132.5f);
                    int y03 = (int)py3, x03 = (int)px3;   // truncation == floor (>0)
                    float wy = py3 - (float)y03, wx = px3 - (float)x03;
                    unsigned uoff = coff[r] + (unsigned)(y03 * 134 + x03);
                    const float* p = padb0 + uoff;
                    float v00 = p[0], v01 = p[1], v10 = p[134], v11 = p[135];
                    float top = v00 + wx * (v01 - v00);
                    float bot = v10 + wx * (v11 - v10);
                    float bil = top + wy * (bot - top);
                    float msk = __builtin_amdgcn_rcpf(1.f + __expf(-lg));
                    s[r] = bil * msk;
                }
                bf16x4 pk = {(bf16)s[0], (bf16)s[1], (bf16)s[2], (bf16)s[3]};
                // row = local px (nf*16+l15); 8B-block cb = wid*4+g, XOR-swizzled
                *(bf16x4*)(sampB + (nf * 16 + l15) * 128
                           + (((wid * 4 + g) ^ ((l15 & 7) << 1)) << 3)) = pk;
            }
        }
        __syncthreads();

        // ---- GEMM2: o-tile = wid, 64 px, K=64 ----
        __builtin_amdgcn_s_setprio(1);
#pragma unroll
        for (int u = 0; u < 4; ++u) {
            const int rb = (u * 16 + l15) * 128;
            bf16x8 b0 = *(const bf16x8*)(sampB + rb + ((g ^ (l15 & 7)) << 4));
            bf16x8 b1 = *(const bf16x8*)(sampB + rb + (((4 + g) ^ (l15 & 7)) << 4));
            acc2[u] = MFMA16(aK0, b0, acc2[u]);
            acc2[u] = MFMA16(aK1, b1, acc2[u]);
        }
        __builtin_amdgcn_s_setprio(0);
        __syncthreads();
    }

    // ---- epilogue: bias + relu, direct stores ----
    float bias[4];
#pragma unroll
    for (int r = 0; r < 4; ++r) bias[r] = dcb[wid * 16 + g * 4 + r];
#pragma unroll
    for (int u = 0; u < 4; ++u)
#pragma unroll
        for (int r = 0; r < 4; ++r) {
            int o = wid * 16 + g * 4 + r;
            out[((size_t)(b * 64 + o) * 128 + h) * 128 + P0 + u * 16 + l15]
                = fmaxf(acc2[u][r] + bias[r], 0.f);
        }
}

// ---------------- launcher ----------------
extern "C" void kernel_launch(void* const* d_in, const int* in_sizes, int n_in,
                              void* d_out, int out_size, void* d_ws, size_t ws_size,
                              hipStream_t stream) {
    const float* inputs = (const float*)d_in[0];
    const float* feat   = (const float*)d_in[1];
    const float* om_w   = (const float*)d_in[2];
    const float* om_b   = (const float*)d_in[3];
    const float* dc_w   = (const float*)d_in[4];
    const float* dc_b   = (const float*)d_in[5];
    float* out = (float*)d_out;

    char* ws = (char*)d_ws;
    bf16*  featS  = (bf16*)(ws + FEATS_OFF);
    bf16*  omw3   = (bf16*)(ws + OMW3_OFF);
    float* ombr   = (float*)(ws + OMB_OFF);
    bf16*  dcw2p  = (bf16*)(ws + DCW_OFF);
    float* pad    = (float*)(ws + PAD_OFF);

    prep_featS<<<dim3(128, 4), 256, 0, stream>>>(feat, featS);
    prep_omw3<<<(995328 + 255) / 256, 256, 0, stream>>>(om_w, omw3);
    prep_dcw2p<<<(36864 + 255) / 256, 256, 0, stream>>>(dc_w, om_b, dcw2p, ombr);
    prep_pad<<<dim3(134, 256), 256, 0, stream>>>(inputs, pad);

    deform_fused<<<1024, 256, 0, stream>>>(pad, featS, omw3, ombr, dcw2p, dc_b, out);
}

// Round 6
// 177.166 us; speedup vs baseline: 2.8170x; 1.0209x over previous
//
#include <hip/hip_runtime.h>
#include <hip/hip_bf16.h>

typedef __bf16 bf16;
typedef __bf16 bf16x8 __attribute__((ext_vector_type(8)));
typedef __bf16 bf16x4 __attribute__((ext_vector_type(4)));
typedef float f32x4 __attribute__((ext_vector_type(4)));
typedef float f32x2 __attribute__((ext_vector_type(2)));
typedef float f32x2u __attribute__((ext_vector_type(2))) __attribute__((aligned(4)));
typedef int  i32x4 __attribute__((ext_vector_type(4)));

#define MFMA16(a, b, c) __builtin_amdgcn_mfma_f32_16x16x32_bf16((a), (b), (c), 0, 0, 0)

// ---- ws layout (bytes) ----
static constexpr size_t FEATS_OFF = 0;                    // featS: 4,194,304 bf16 = 8,388,608
static constexpr size_t OMW3_OFF  = 8388608;              // 995,328 bf16 = 1,990,656
static constexpr size_t DCW_OFF   = OMW3_OFF + 1990656;   // 36,864 bf16  = 73,728
static constexpr size_t SC_OFF    = DCW_OFF + 73728;      // 576 f32x4    = 9,216
static constexpr size_t PAD_OFF   = SC_OFF + 9216;        // 256*134*134 f32 = 18,386,944

// ---------------- prep kernels ----------------

// feat [b][cf][hh][px] f32 -> featS [b][hh][px][cf swizzled] bf16
// swizzle within 128B row: cf=cfb*8+e at 16B-block (cfb ^ (px&7)), slot e
__global__ void prep_featS(const float* __restrict__ feat, bf16* __restrict__ featS) {
    const int hh = blockIdx.x, b = blockIdx.y;
    __shared__ float t[64][129];
    for (int i = threadIdx.x; i < 64 * 32; i += 256) {
        int cf = i >> 5, q = i & 31;
        const float* src = feat + ((size_t)(b * 64 + cf) * 128 + hh) * 128 + q * 4;
        t[cf][q * 4 + 0] = src[0];
        t[cf][q * 4 + 1] = src[1];
        t[cf][q * 4 + 2] = src[2];
        t[cf][q * 4 + 3] = src[3];
    }
    __syncthreads();
    for (int i = threadIdx.x; i < 1024; i += 256) {
        int px = i >> 3, cfb = i & 7;
        int sb = cfb ^ (px & 7);
        bf16x8 v;
#pragma unroll
        for (int e = 0; e < 8; ++e) v[e] = (bf16)t[cfb * 8 + e][px];
        *(bf16x8*)(featS + ((size_t)((b * 128 + hh) * 128 + px) << 6) + sb * 8) = v;
    }
}

// omw3[ctile 36][kk 18][t 3][lane 64][j 8] ; dcw2p[win 18][ot 4][lane 64][j 8] ;
// sconst pairs: floats[pr*8 +{0,1}=ybias, {2,3}=xbias, {4,5}=mbias, {6,7}=coff bits]
__global__ void prep_weights(const float* __restrict__ om_w, const float* __restrict__ om_b,
                             const float* __restrict__ dc_w,
                             bf16* __restrict__ omw3, bf16* __restrict__ dcw2p,
                             float* __restrict__ scf) {
    int i = blockIdx.x * 256 + threadIdx.x;
    if (i < 995328) {
        int e = i & 511, lane = e >> 3, j = e & 7;
        int q = i >> 9;
        int t = q % 3, q2 = q / 3, kk = q2 % 18, ct = q2 / 18;
        int ck = ct * 16 + (lane & 15);
        int kcol = kk * 32 + (lane >> 4) * 8 + j;
        int tap = kcol >> 6, cf = kcol & 63;
        int ch = (t < 2) ? (ck * 2 + t) : (1152 + ck);
        omw3[i] = (bf16)om_w[ch * 576 + cf * 9 + tap];
    }
    if (i < 36864) {
        int j = i & 7, lane = (i >> 3) & 63, ot = (i >> 9) & 3, win = i >> 11;
        int o = ot * 16 + (lane & 15);
        int ck = win * 32 + (lane >> 4) * 8 + j;
        dcw2p[i] = (bf16)dc_w[o * 576 + ck];
    }
    if (i < 576) {
        int ck = i;
        int c = ck / 9, kd = ck - 9 * c, kq = kd / 3, kx = kd - 3 * kq;
        int pr = ck >> 1, lo = ck & 1;
        scf[pr * 8 + 0 + lo] = om_b[ck * 2]     + (float)(kq + 2);
        scf[pr * 8 + 2 + lo] = om_b[ck * 2 + 1] + (float)(kx + 2);
        scf[pr * 8 + 4 + lo] = om_b[1152 + ck];
        scf[pr * 8 + 6 + lo] = __uint_as_float((unsigned)(c * 17956));
    }
}

// inputs [256][128][128] -> zero-padded pad [256][134][134] (3-px border)
__global__ void prep_pad(const float* __restrict__ inputs, float* __restrict__ pad) {
    int yy = blockIdx.x, bc = blockIdx.y, xx = threadIdx.x;
    if (xx >= 134) return;
    float v = 0.f;
    if (yy >= 3 && yy <= 130 && xx >= 3 && xx <= 130)
        v = inputs[(size_t)bc * 16384 + (yy - 3) * 128 + (xx - 3)];
    pad[((size_t)bc * 134 + yy) * 134 + xx] = v;
}

// ---------------- fused main kernel ----------------
// grid 1024 = (b, h, pxhalf); 4 waves = ck-quarters. Same phase structure as R5;
// this round is an instruction diet: scalar-base weight addressing, hoisted
// LDS bases, med3/fract/dwordx2/pk-add sampling, paired sconst table.

__global__ void __launch_bounds__(256, 4)
deform_fused(const float* __restrict__ pad,
             const bf16* __restrict__ featS,
             const bf16* __restrict__ omw3,
             const bf16* __restrict__ dcw2p,
             const f32x4* __restrict__ sconst,
             const float* __restrict__ dcb,
             float* __restrict__ out)
{
    const int bid = blockIdx.x;
    const int P0 = (bid & 1) << 6;
    const int h = (bid >> 1) & 127;
    const int b = bid >> 8;
    const int tid = threadIdx.x;
    const int lane = tid & 63;
    const int wid_s = __builtin_amdgcn_readfirstlane(tid >> 6);
    const int l15 = lane & 15, g = lane >> 4;

    __shared__ __align__(16) unsigned char smem[25344 + 8192];
    char* featB = (char*)smem;           // [3 ky][66 q][128B], swizzle rides from featS
    char* sampB = (char*)smem + 25344;   // [64 px][128B = 64 ck]

    // zero featB (halo cols / OOB rows stay 0)
    for (int i = tid; i < 6336; i += 256) ((unsigned*)featB)[i] = 0u;
    __syncthreads();
    // bulk-stage 3 rows x 65 px-cols x 128B from featS
    {
        const int s0 = (P0 == 0) ? 0 : 63;
        const int q0 = (P0 == 0) ? 1 : 0;
        for (int i = tid; i < 1560; i += 256) {
            int ky = i / 520, rem = i - ky * 520, row = rem >> 3, c = rem & 7;
            int hh = h - 1 + ky;
            if ((unsigned)hh < 128u) {
                const char* src = (const char*)featS
                    + (((size_t)(b * 128 + hh) * 128 + s0 + row) << 7) + c * 16;
                *(i32x4*)(featB + ((ky * 66 + q0 + row) << 7) + c * 16) = *(const i32x4*)src;
            }
        }
    }
    __syncthreads();

    // hoisted blk-invariant featB bases (18 regs)
    int fb[18];
#pragma unroll
    for (int kk = 0; kk < 18; ++kk) {
        const int tap = kk >> 1;
        const int kyp = tap / 3, kxp = tap - 3 * kyp;
        const int q = l15 + kxp;
        fb[kk] = (kyp * 66 + q) * 128 + ((((kk & 1) * 4 + g) ^ ((q + 7) & 7)) << 4);
    }

    f32x4 acc2[4];
#pragma unroll
    for (int u = 0; u < 4; ++u) acc2[u] = (f32x4){0.f, 0.f, 0.f, 0.f};

    const bf16* omw3_l = omw3 + lane * 8;
    const bf16* dcw_l  = dcw2p + lane * 8;
    const float* padb0 = pad + (size_t)b * 64 * 17956;
    const f32x2 hb2 = {(float)h, (float)h};
    const f32x2 fx2 = {(float)(P0 + l15), (float)(P0 + l15)};
    const int g4 = g * 4;

#pragma unroll 1
    for (int blk = 0; blk < 9; ++blk) {
        // ---- GEMM1: this wave's 16 cks x 3 types x 64 px ----
        f32x4 acc1[3][4];
#pragma unroll
        for (int t = 0; t < 3; ++t)
#pragma unroll
            for (int nf = 0; nf < 4; ++nf) acc1[t][nf] = (f32x4){0.f, 0.f, 0.f, 0.f};

        const int abase = (blk * 4 + wid_s) * 27648;   // scalar

#pragma unroll
        for (int kk = 0; kk < 18; ++kk) {
            bf16x8 a0 = *(const bf16x8*)(omw3_l + abase + ((kk * 3 + 0) << 9));
            bf16x8 a1 = *(const bf16x8*)(omw3_l + abase + ((kk * 3 + 1) << 9));
            bf16x8 a2 = *(const bf16x8*)(omw3_l + abase + ((kk * 3 + 2) << 9));
            bf16x8 bfr[4];
#pragma unroll
            for (int nf = 0; nf < 4; ++nf)
                bfr[nf] = *(const bf16x8*)(featB + fb[kk] + nf * 2048);
            __builtin_amdgcn_s_setprio(1);
#pragma unroll
            for (int nf = 0; nf < 4; ++nf) {
                acc1[0][nf] = MFMA16(a0, bfr[nf], acc1[0][nf]);
                acc1[1][nf] = MFMA16(a1, bfr[nf], acc1[1][nf]);
                acc1[2][nf] = MFMA16(a2, bfr[nf], acc1[2][nf]);
            }
            __builtin_amdgcn_s_setprio(0);
        }

        // GEMM2 A-frags (independent, issue early)
        bf16x8 aK0 = *(const bf16x8*)(dcw_l + ((blk * 8 + wid_s) << 9));
        bf16x8 aK1 = *(const bf16x8*)(dcw_l + ((blk * 8 + 4 + wid_s) << 9));

        // ---- per-blk sample constants (paired) ----
        const f32x4* scB = sconst + (blk * 64 + wid_s * 16);
        f32x4 e0A = scB[g4 + 0], e1A = scB[g4 + 1];
        f32x4 e0B = scB[g4 + 2], e1B = scB[g4 + 3];
        f32x2 yb[2], xb[2], mb[2];
        unsigned co[2][2];
        yb[0] = f32x2{e0A.x, e0A.y} + hb2;
        xb[0] = f32x2{e0A.z, e0A.w} + fx2;
        mb[0] = f32x2{e1A.x, e1A.y};
        co[0][0] = __float_as_uint(e1A.z); co[0][1] = __float_as_uint(e1A.w);
        yb[1] = f32x2{e0B.x, e0B.y} + hb2;
        xb[1] = f32x2{e0B.z, e0B.w} + fx2;
        mb[1] = f32x2{e1B.x, e1B.y};
        co[1][0] = __float_as_uint(e1B.z); co[1][1] = __float_as_uint(e1B.w);

        // ---- sample: 4 nf x (2 pairs x 2) per lane ----
#pragma unroll
        for (int nf = 0; nf < 4; ++nf) {
            float s[4];
#pragma unroll
            for (int pi = 0; pi < 2; ++pi) {
                f32x2 py = f32x2{acc1[0][nf][2 * pi], acc1[0][nf][2 * pi + 1]} + yb[pi];
                f32x2 px = f32x2{acc1[1][nf][2 * pi], acc1[1][nf][2 * pi + 1]} + xb[pi];
                f32x2 lg = f32x2{acc1[2][nf][2 * pi], acc1[2][nf][2 * pi + 1]} + mb[pi];
#pragma unroll
                for (int e = 0; e < 2; ++e) {
                    float pyc = __builtin_amdgcn_fmed3f(py[e], 0.5f, 132.5f);
                    float pxc = __builtin_amdgcn_fmed3f(px[e], 0.5f, 132.5f);
                    int y0 = (int)pyc, x0 = (int)pxc;      // trunc == floor (>0)
                    float wy = __builtin_amdgcn_fractf(pyc);
                    float wx = __builtin_amdgcn_fractf(pxc);
                    unsigned off = co[pi][e] + (unsigned)(y0 * 134 + x0);
                    f32x2u t0 = *(const f32x2u*)(padb0 + off);        // v00,v01
                    f32x2u t1 = *(const f32x2u*)(padb0 + off + 134);  // v10,v11
                    float top = t0.x + wx * (t0.y - t0.x);
                    float bot = t1.x + wx * (t1.y - t1.x);
                    float bil = top + wy * (bot - top);
                    float mk = __builtin_amdgcn_rcpf(1.f + __expf(-lg[e]));
                    s[2 * pi + e] = bil * mk;
                }
            }
            bf16x4 pk4 = {(bf16)s[0], (bf16)s[1], (bf16)s[2], (bf16)s[3]};
            *(bf16x4*)(sampB + (nf * 16 + l15) * 128
                       + (((wid_s * 4 + g) ^ ((l15 & 7) << 1)) << 3)) = pk4;
            xb[0] += 16.f; xb[1] += 16.f;
        }
        __syncthreads();

        // ---- GEMM2: o-tile = wid, 64 px, K=64 ----
        const int rb_swz = (g ^ (l15 & 7)) << 4;
        __builtin_amdgcn_s_setprio(1);
#pragma unroll
        for (int u = 0; u < 4; ++u) {
            const int rb = (u * 16 + l15) * 128 + rb_swz;
            bf16x8 b0 = *(const bf16x8*)(sampB + rb);
            bf16x8 b1 = *(const bf16x8*)(sampB + (rb ^ 64));
            acc2[u] = MFMA16(aK0, b0, acc2[u]);
            acc2[u] = MFMA16(aK1, b1, acc2[u]);
        }
        __builtin_amdgcn_s_setprio(0);
        __syncthreads();
    }

    // ---- epilogue: bias + relu, direct stores ----
    float bias[4];
#pragma unroll
    for (int r = 0; r < 4; ++r) bias[r] = dcb[wid_s * 16 + g * 4 + r];
#pragma unroll
    for (int u = 0; u < 4; ++u)
#pragma unroll
        for (int r = 0; r < 4; ++r) {
            int o = wid_s * 16 + g * 4 + r;
            out[((size_t)(b * 64 + o) * 128 + h) * 128 + P0 + u * 16 + l15]
                = fmaxf(acc2[u][r] + bias[r], 0.f);
        }
}

// ---------------- launcher ----------------
extern "C" void kernel_launch(void* const* d_in, const int* in_sizes, int n_in,
                              void* d_out, int out_size, void* d_ws, size_t ws_size,
                              hipStream_t stream) {
    const float* inputs = (const float*)d_in[0];
    const float* feat   = (const float*)d_in[1];
    const float* om_w   = (const float*)d_in[2];
    const float* om_b   = (const float*)d_in[3];
    const float* dc_w   = (const float*)d_in[4];
    const float* dc_b   = (const float*)d_in[5];
    float* out = (float*)d_out;

    char* ws = (char*)d_ws;
    bf16*  featS  = (bf16*)(ws + FEATS_OFF);
    bf16*  omw3   = (bf16*)(ws + OMW3_OFF);
    bf16*  dcw2p  = (bf16*)(ws + DCW_OFF);
    float* scf    = (float*)(ws + SC_OFF);
    float* pad    = (float*)(ws + PAD_OFF);

    prep_featS<<<dim3(128, 4), 256, 0, stream>>>(feat, featS);
    prep_weights<<<(995328 + 255) / 256, 256, 0, stream>>>(om_w, om_b, dc_w, omw3, dcw2p, scf);
    prep_pad<<<dim3(134, 256), 256, 0, stream>>>(inputs, pad);

    deform_fused<<<1024, 256, 0, stream>>>(pad, featS, omw3, dcw2p,
                                           (const f32x4*)scf, dc_b, out);
}